// Round 6
// baseline (790.061 us; speedup 1.0000x reference)
//
#include <hip/hip_runtime.h>

typedef __attribute__((ext_vector_type(8))) short bf16x8;
typedef __attribute__((ext_vector_type(4))) float f32x4;
typedef __attribute__((ext_vector_type(4))) float f4v;

__device__ __forceinline__ unsigned short f2bf(float f){
  unsigned u = __builtin_bit_cast(unsigned, f);
  u += 0x7FFFu + ((u >> 16) & 1u);
  return (unsigned short)(u >> 16);
}
__device__ __forceinline__ float bf2f(unsigned short b){
  unsigned u = ((unsigned)b) << 16;
  return __builtin_bit_cast(float, u);
}
__device__ __forceinline__ float sigmoidf_(float x){ return 1.f/(1.f + __expf(-x)); }
__device__ __forceinline__ float tanhf_(float x){
  float a = fabsf(x);
  float t = __expf(-2.f*a);
  float r = (1.f - t)/(1.f + t);
  return copysignf(r, x);
}

struct WF { bf16x8 hi, lo; };

// split-precision accumulate: hi-chain gets ah*Bhi, lo-chain gets al*Bhi + ah*Blo
__device__ __forceinline__ void mmsplit(bf16x8 ah, bf16x8 al, const WF& B,
                                        f32x4& Dh, f32x4& Dl){
  Dh = __builtin_amdgcn_mfma_f32_16x16x32_bf16(ah, B.hi, Dh, 0, 0, 0);
  Dl = __builtin_amdgcn_mfma_f32_16x16x32_bf16(al, B.hi, Dl, 0, 0, 0);
  Dl = __builtin_amdgcn_mfma_f32_16x16x32_bf16(ah, B.lo, Dl, 0, 0, 0);
}

__device__ __forceinline__ WF load_wf(const float* W, int ldk, int row, int k0, int kmax){
  WF f;
  #pragma unroll
  for (int j = 0; j < 8; j++){
    int k = k0 + j;
    float v = (k < kmax) ? W[row*ldk + k] : 0.f;
    unsigned short hb = f2bf(v);
    f.hi[j] = (short)hb;
    f.lo[j] = (short)f2bf(v - bf2f(hb));
  }
  return f;
}

#define NPRE 262   // row-pairs whose masks are precomputed in kernel 1

// ---- kernel 1: blocks 0-249 = GRU (split-wave pipeline + fused ac epilogue);
// ----           blocks 250-511 = mask precompute (hidden under GRU's latency) ----
__global__ __launch_bounds__(512, 2)
void gru_kernel(const float* __restrict__ x, const float* __restrict__ rel,
                const float* __restrict__ Wih0, const float* __restrict__ Whh0,
                const float* __restrict__ bih0, const float* __restrict__ bhh0,
                const float* __restrict__ Wih1, const float* __restrict__ Whh1,
                const float* __restrict__ bih1, const float* __restrict__ bhh1,
                const float* __restrict__ W0h, const float* __restrict__ W1h,
                const float* __restrict__ W2h,
                const float* __restrict__ fcw, const float* __restrict__ fcb,
                float* __restrict__ ac, unsigned char* __restrict__ mask8){
  __shared__ unsigned short xp_hi[16][60][8];
  __shared__ unsigned short xp_lo[16][60][8];
  __shared__ unsigned short h0hi[2][16][72], h0lo[2][16][72];
  __shared__ unsigned short h1hi[2][16][72], h1lo[2][16][72];
  __shared__ float hsh[16][64];

  const int tid  = threadIdx.x;

  if (blockIdx.x >= 250){
    // independent mask-precompute blocks: stream 2 rel rows, write u8 sums.
    // Runs concurrently with the GRU blocks (GRU is latency-bound, not BW).
    const int u = blockIdx.x - 250;          // 0..261
    const size_t r0 = (size_t)(2*u)*4000;
    const size_t r1 = r0 + 4000;
    for (int j = tid; j < 4000; j += 512){
      const f4v* rp0 = (const f4v*)(rel + (r0 + j)*8);
      const f4v* rp1 = (const f4v*)(rel + (r1 + j)*8);
      f4v a0 = __builtin_nontemporal_load(rp0);
      f4v a1 = __builtin_nontemporal_load(rp0 + 1);
      f4v a2 = __builtin_nontemporal_load(rp1);
      f4v a3 = __builtin_nontemporal_load(rp1 + 1);
      float mk0 = a0[0]+a0[1]+a0[2]+a0[3] + a1[0]+a1[1]+a1[2]+a1[3];
      float mk1 = a2[0]+a2[1]+a2[2]+a2[3] + a3[0]+a3[1]+a3[2]+a3[3];
      mask8[r0 + j] = (unsigned char)(int)mk0;
      mask8[r1 + j] = (unsigned char)(int)mk1;
    }
    return;
  }

  const int lane = tid & 63;
  const int wv   = tid >> 6;          // 0..7
  const bool isA = (wv < 4);          // wave-uniform
  const int w    = wv & 3;
  const int c    = lane & 15;
  const int q    = lane >> 4;
  const int d    = w*16 + c;
  const int nbase = blockIdx.x * 16;

  for (int v = tid; v < 16*360; v += 512){
    int n = v / 360, rem = v % 360;
    int dd = rem / 60, tt = rem % 60;
    float f = x[(size_t)(nbase + n)*360 + rem];
    unsigned short hb = f2bf(f);
    xp_hi[n][tt][dd] = hb;
    xp_lo[n][tt][dd] = f2bf(f - bf2f(hb));
  }
  for (int v = tid; v < 16*60*2; v += 512){
    int n = v / 120, rem = v % 120;
    int tt = rem >> 1, dd = 6 + (rem & 1);
    xp_hi[n][tt][dd] = 0; xp_lo[n][tt][dd] = 0;
  }
  for (int v = tid; v < 2*16*72; v += 512){
    ((unsigned short*)h0hi)[v] = 0; ((unsigned short*)h0lo)[v] = 0;
    ((unsigned short*)h1hi)[v] = 0; ((unsigned short*)h1lo)[v] = 0;
  }

  const float* bib = isA ? bih0 : bih1;
  const float* bhb = isA ? bhh0 : bhh1;
  const float bir = bib[d], biz = bib[64+d], bin = bib[128+d];
  const float bhr = bhb[d], bhz = bhb[64+d], bhn = bhb[128+d];

  WF Bu[3][2], Bv[3][2];
  #pragma unroll
  for (int g = 0; g < 3; g++){
    int row = g*64 + d;
    if (isA){
      Bu[g][0] = load_wf(Wih0, 6, row, q*8, 6);
      Bu[g][1] = Bu[g][0];
      #pragma unroll
      for (int kt = 0; kt < 2; kt++)
        Bv[g][kt] = load_wf(Whh0, 64, row, kt*32 + q*8, 64);
    } else {
      #pragma unroll
      for (int kt = 0; kt < 2; kt++){
        Bu[g][kt] = load_wf(Wih1, 64, row, kt*32 + q*8, 64);
        Bv[g][kt] = load_wf(Whh1, 64, row, kt*32 + q*8, 64);
      }
    }
  }

  float hold[4] = {0,0,0,0};

  auto stepB = [&](int s){
    const int rb = (s + 1) & 1;
    const int sb = s & 1;
    bf16x8 ayh[2], ayl[2], ahh[2], ahl[2];
    #pragma unroll
    for (int kt = 0; kt < 2; kt++){
      ayh[kt] = *(const bf16x8*)&h0hi[rb][c][kt*32 + q*8];
      ayl[kt] = *(const bf16x8*)&h0lo[rb][c][kt*32 + q*8];
      ahh[kt] = *(const bf16x8*)&h1hi[sb][c][kt*32 + q*8];
      ahl[kt] = *(const bf16x8*)&h1lo[sb][c][kt*32 + q*8];
    }
    f32x4 RH = {0,0,0,0}, RL = {0,0,0,0};
    f32x4 ZH = {0,0,0,0}, ZL = {0,0,0,0};
    f32x4 NIH = {0,0,0,0}, NIL = {0,0,0,0};
    f32x4 NHH = {0,0,0,0}, NHL = {0,0,0,0};
    #pragma unroll
    for (int kt = 0; kt < 2; kt++){
      mmsplit(ayh[kt], ayl[kt], Bu[0][kt], RH, RL);
      mmsplit(ayh[kt], ayl[kt], Bu[1][kt], ZH, ZL);
      mmsplit(ayh[kt], ayl[kt], Bu[2][kt], NIH, NIL);
      mmsplit(ahh[kt], ahl[kt], Bv[0][kt], RH, RL);
      mmsplit(ahh[kt], ahl[kt], Bv[1][kt], ZH, ZL);
      mmsplit(ahh[kt], ahl[kt], Bv[2][kt], NHH, NHL);
    }
    #pragma unroll
    for (int rI = 0; rI < 4; rI++){
      float rv = sigmoidf_(RH[rI] + RL[rI] + bir + bhr);
      float zv = sigmoidf_(ZH[rI] + ZL[rI] + biz + bhz);
      float nv = tanhf_(NIH[rI] + NIL[rI] + bin + rv*(NHH[rI] + NHL[rI] + bhn));
      float hnew = (1.f - zv)*nv + zv*hold[rI];
      hold[rI] = hnew;
      unsigned short hb = f2bf(hnew);
      int node = q*4 + rI;
      h1hi[rb][node][d] = hb;
      h1lo[rb][node][d] = f2bf(hnew - bf2f(hb));
    }
  };

  __syncthreads();

  #pragma unroll 1
  for (int t = 0; t < 60; t++){
    if (isA){
      const int p  = t & 1;
      const int nb = p ^ 1;
      bf16x8 ah[2], al[2];
      #pragma unroll
      for (int kt = 0; kt < 2; kt++){
        ah[kt] = *(const bf16x8*)&h0hi[p][c][kt*32 + q*8];
        al[kt] = *(const bf16x8*)&h0lo[p][c][kt*32 + q*8];
      }
      bf16x8 axh = {}, axl = {};
      if (q == 0){
        axh = *(const bf16x8*)&xp_hi[c][t][0];
        axl = *(const bf16x8*)&xp_lo[c][t][0];
      }
      f32x4 RH = {0,0,0,0}, RL = {0,0,0,0};
      f32x4 ZH = {0,0,0,0}, ZL = {0,0,0,0};
      f32x4 NIH = {0,0,0,0}, NIL = {0,0,0,0};
      f32x4 NHH = {0,0,0,0}, NHL = {0,0,0,0};
      mmsplit(axh, axl, Bu[0][0], RH, RL);
      mmsplit(axh, axl, Bu[1][0], ZH, ZL);
      mmsplit(axh, axl, Bu[2][0], NIH, NIL);
      #pragma unroll
      for (int kt = 0; kt < 2; kt++){
        mmsplit(ah[kt], al[kt], Bv[0][kt], RH, RL);
        mmsplit(ah[kt], al[kt], Bv[1][kt], ZH, ZL);
        mmsplit(ah[kt], al[kt], Bv[2][kt], NHH, NHL);
      }
      #pragma unroll
      for (int rI = 0; rI < 4; rI++){
        float rv = sigmoidf_(RH[rI] + RL[rI] + bir + bhr);
        float zv = sigmoidf_(ZH[rI] + ZL[rI] + biz + bhz);
        float nv = tanhf_(NIH[rI] + NIL[rI] + bin + rv*(NHH[rI] + NHL[rI] + bhn));
        float hnew = (1.f - zv)*nv + zv*hold[rI];
        hold[rI] = hnew;
        unsigned short hb = f2bf(hnew);
        int node = q*4 + rI;
        h0hi[nb][node][d] = hb;
        h0lo[nb][node][d] = f2bf(hnew - bf2f(hb));
      }
    } else if (t > 0){
      stepB(t - 1);
    }
    __syncthreads();
  }

  if (!isA){
    stepB(59);
    #pragma unroll
    for (int rI = 0; rI < 4; rI++)
      hsh[q*4 + rI][d] = hold[rI];
  }
  __syncthreads();

  // fused ac epilogue: all 8 waves, 2 nodes each (bit-identical to old ac_kernel)
  {
    const float w0a = W0h[lane], w0c = W0h[64 + lane];
    const float w1a = W1h[lane], w1c = W1h[64 + lane];
    const float w2a = W2h[lane], w2c = W2h[64 + lane];
    const float gw  = fcw[64 + lane], pw = fcw[lane];
    #pragma unroll
    for (int nn = 0; nn < 2; nn++){
      int n = wv*2 + nn;
      float hv = hsh[n][lane];
      float pa0 = hv*w0a, pc0 = hv*w0c;
      float pa1 = hv*w1a, pc1 = hv*w1c;
      float pa2 = hv*w2a, pc2 = hv*w2c;
      float pg  = hv*gw,  pp  = hv*pw;
      #pragma unroll
      for (int m = 32; m >= 1; m >>= 1){
        pa0 += __shfl_xor(pa0, m, 64); pc0 += __shfl_xor(pc0, m, 64);
        pa1 += __shfl_xor(pa1, m, 64); pc1 += __shfl_xor(pc1, m, 64);
        pa2 += __shfl_xor(pa2, m, 64); pc2 += __shfl_xor(pc2, m, 64);
        pg  += __shfl_xor(pg,  m, 64); pp  += __shfl_xor(pp,  m, 64);
      }
      if (lane == 0){
        size_t node = (size_t)(nbase + n);
        ac[0*4000 + node] = pa0; ac[1*4000 + node] = pc0;
        ac[2*4000 + node] = pa1; ac[3*4000 + node] = pc1;
        ac[4*4000 + node] = pa2; ac[5*4000 + node] = pc2;
        ac[6*4000 + node] = pg;  ac[7*4000 + node] = pp + fcb[0];
      }
    }
  }
}

// -------- single-pass fused attention: z_h = Σ exp(v), y_h = Σ exp(v)·g[j] --------
// Blocks < NPRE read precomputed u8 masks (no rel traffic); the rest stream rel.
__global__ __launch_bounds__(256, 4)
void attn2_kernel(const float* __restrict__ rel,
                  const unsigned char* __restrict__ mask8,
                  const float* __restrict__ ac,
                  const float* __restrict__ b0p, const float* __restrict__ b1p,
                  const float* __restrict__ b2p, float* __restrict__ pred){
  __shared__ float red[4][12];

  const int tid  = threadIdx.x;
  const int lane = tid & 63;
  const int w    = tid >> 6;
  const int i0   = blockIdx.x * 2;
  const float bh[3] = {b0p[0], b1p[0], b2p[0]};

  const float* c0 = ac + (size_t)1*4000;
  const float* c1 = ac + (size_t)3*4000;
  const float* c2 = ac + (size_t)5*4000;
  const float* gv = ac + (size_t)6*4000;
  const float* p0 = ac + (size_t)7*4000;

  float ai[2][3];
  #pragma unroll
  for (int r = 0; r < 2; r++)
    #pragma unroll
    for (int h = 0; h < 3; h++)
      ai[r][h] = ac[(size_t)(2*h)*4000 + i0 + r];

  float z[2][3] = {{0.f,0.f,0.f},{0.f,0.f,0.f}};
  float y[2][3] = {{0.f,0.f,0.f},{0.f,0.f,0.f}};

  auto body = [&](float mk0, float mk1, int j){
    float cv[3] = {c0[j], c1[j], c2[j]};
    float gj = gv[j];
    #pragma unroll
    for (int h = 0; h < 3; h++){
      float s0 = ai[0][h] + cv[h] + bh[h];
      float s1 = ai[1][h] + cv[h] + bh[h];
      float w0 = s0 > 0.f ? s0 : 0.01f*s0;
      float w1 = s1 > 0.f ? s1 : 0.01f*s1;
      float v0 = (mk0 == 0.f) ? -1e6f : mk0*w0;
      float v1 = (mk1 == 0.f) ? -1e6f : mk1*w1;
      float e0 = __expf(v0);
      float e1 = __expf(v1);
      z[0][h] += e0;  y[0][h] = fmaf(e0, gj, y[0][h]);
      z[1][h] += e1;  y[1][h] = fmaf(e1, gj, y[1][h]);
    }
  };

  if (blockIdx.x < NPRE){
    // masks precomputed in kernel 1 -> no rel traffic at all
    const size_t m0b = (size_t)i0*4000;
    const size_t m1b = m0b + 4000;
    for (int j = tid; j < 4000; j += 256){
      float mk0 = (float)mask8[m0b + j];
      float mk1 = (float)mask8[m1b + j];
      body(mk0, mk1, j);
    }
  } else {
    // stream rel with depth-2 register prefetch
    const size_t base0 = (size_t)i0*4000;
    const size_t base1 = (size_t)(i0+1)*4000;
    int j = tid;
    bool hv0 = (j < 4000);
    bool hv1 = (j + 256 < 4000);
    f4v a0, a1, a2, a3, b0, b1, b2, b3;
    if (hv0){
      const f4v* rp0 = (const f4v*)(rel + (base0 + j)*8);
      const f4v* rp1 = (const f4v*)(rel + (base1 + j)*8);
      a0 = __builtin_nontemporal_load(rp0);
      a1 = __builtin_nontemporal_load(rp0 + 1);
      a2 = __builtin_nontemporal_load(rp1);
      a3 = __builtin_nontemporal_load(rp1 + 1);
    }
    if (hv1){
      const f4v* rp0 = (const f4v*)(rel + (base0 + j + 256)*8);
      const f4v* rp1 = (const f4v*)(rel + (base1 + j + 256)*8);
      b0 = __builtin_nontemporal_load(rp0);
      b1 = __builtin_nontemporal_load(rp0 + 1);
      b2 = __builtin_nontemporal_load(rp1);
      b3 = __builtin_nontemporal_load(rp1 + 1);
    }
    while (hv0){
      int j2 = j + 512;
      bool hv2 = (j2 < 4000);
      f4v n0, n1, n2, n3;
      if (hv2){
        const f4v* rp0 = (const f4v*)(rel + (base0 + j2)*8);
        const f4v* rp1 = (const f4v*)(rel + (base1 + j2)*8);
        n0 = __builtin_nontemporal_load(rp0);
        n1 = __builtin_nontemporal_load(rp0 + 1);
        n2 = __builtin_nontemporal_load(rp1);
        n3 = __builtin_nontemporal_load(rp1 + 1);
      }
      float mk0 = a0[0]+a0[1]+a0[2]+a0[3] + a1[0]+a1[1]+a1[2]+a1[3];
      float mk1 = a2[0]+a2[1]+a2[2]+a2[3] + a3[0]+a3[1]+a3[2]+a3[3];
      body(mk0, mk1, j);
      a0 = b0; a1 = b1; a2 = b2; a3 = b3;
      b0 = n0; b1 = n1; b2 = n2; b3 = n3;
      j += 256; hv0 = hv1; hv1 = hv2;
    }
  }

  // wave-reduce 12 (z,y) pairs, then cross-wave via tiny LDS
  #pragma unroll
  for (int r = 0; r < 2; r++)
    #pragma unroll
    for (int h = 0; h < 3; h++){
      float vz = z[r][h], vy = y[r][h];
      #pragma unroll
      for (int m = 32; m >= 1; m >>= 1){
        vz += __shfl_xor(vz, m, 64);
        vy += __shfl_xor(vy, m, 64);
      }
      if (lane == 0){
        red[w][(r*3 + h)*2 + 0] = vz;
        red[w][(r*3 + h)*2 + 1] = vy;
      }
    }
  __syncthreads();
  if (tid < 2){
    int r = tid;
    float acc = 0.f;
    #pragma unroll
    for (int h = 0; h < 3; h++){
      float zz = red[0][(r*3+h)*2] + red[1][(r*3+h)*2] + red[2][(r*3+h)*2] + red[3][(r*3+h)*2];
      float yy = red[0][(r*3+h)*2+1] + red[1][(r*3+h)*2+1] + red[2][(r*3+h)*2+1] + red[3][(r*3+h)*2+1];
      acc += yy / zz;
    }
    pred[i0 + r] = p0[i0 + r] + acc * (1.f/3.f);
  }
}

extern "C" void kernel_launch(void* const* d_in, const int* in_sizes, int n_in,
                              void* d_out, int out_size, void* d_ws, size_t ws_size,
                              hipStream_t stream) {
  const float* x    = (const float*)d_in[0];
  const float* rel  = (const float*)d_in[1];
  const float* Wih0 = (const float*)d_in[2];
  const float* Whh0 = (const float*)d_in[3];
  const float* bih0 = (const float*)d_in[4];
  const float* bhh0 = (const float*)d_in[5];
  const float* Wih1 = (const float*)d_in[6];
  const float* Whh1 = (const float*)d_in[7];
  const float* bih1 = (const float*)d_in[8];
  const float* bhh1 = (const float*)d_in[9];
  const float* W0   = (const float*)d_in[10];
  const float* b0   = (const float*)d_in[11];
  const float* W1   = (const float*)d_in[12];
  const float* b1   = (const float*)d_in[13];
  const float* W2   = (const float*)d_in[14];
  const float* b2   = (const float*)d_in[15];
  const float* fcw  = (const float*)d_in[16];
  const float* fcb  = (const float*)d_in[17];
  float* pred = (float*)d_out;
  float* ac   = (float*)d_ws;                              // 8*4000 f32
  unsigned char* mask8 = (unsigned char*)(ac + 8*4000);    // 2*NPRE rows * 4000 u8

  gru_kernel<<<dim3(512), dim3(512), 0, stream>>>(x, rel, Wih0, Whh0, bih0, bhh0,
                                                  Wih1, Whh1, bih1, bhh1,
                                                  W0, W1, W2, fcw, fcb, ac, mask8);
  attn2_kernel<<<dim3(2000), dim3(256), 0, stream>>>(rel, mask8, ac, b0, b1, b2, pred);
}

// Round 7
// 774.683 us; speedup vs baseline: 1.0198x; 1.0198x over previous
//
#include <hip/hip_runtime.h>

typedef __attribute__((ext_vector_type(8))) short bf16x8;
typedef __attribute__((ext_vector_type(4))) float f32x4;
typedef __attribute__((ext_vector_type(4))) float f4v;

__device__ __forceinline__ unsigned short f2bf(float f){
  unsigned u = __builtin_bit_cast(unsigned, f);
  u += 0x7FFFu + ((u >> 16) & 1u);
  return (unsigned short)(u >> 16);
}
__device__ __forceinline__ float bf2f(unsigned short b){
  unsigned u = ((unsigned)b) << 16;
  return __builtin_bit_cast(float, u);
}
__device__ __forceinline__ float sigmoidf_(float x){ return 1.f/(1.f + __expf(-x)); }
__device__ __forceinline__ float tanhf_(float x){
  float a = fabsf(x);
  float t = __expf(-2.f*a);
  float r = (1.f - t)/(1.f + t);
  return copysignf(r, x);
}

struct WF { bf16x8 hi, lo; };

// split-precision accumulate: hi-chain gets ah*Bhi, lo-chain gets al*Bhi + ah*Blo
__device__ __forceinline__ void mmsplit(bf16x8 ah, bf16x8 al, const WF& B,
                                        f32x4& Dh, f32x4& Dl){
  Dh = __builtin_amdgcn_mfma_f32_16x16x32_bf16(ah, B.hi, Dh, 0, 0, 0);
  Dl = __builtin_amdgcn_mfma_f32_16x16x32_bf16(al, B.hi, Dl, 0, 0, 0);
  Dl = __builtin_amdgcn_mfma_f32_16x16x32_bf16(ah, B.lo, Dl, 0, 0, 0);
}

__device__ __forceinline__ WF load_wf(const float* W, int ldk, int row, int k0, int kmax){
  WF f;
  #pragma unroll
  for (int j = 0; j < 8; j++){
    int k = k0 + j;
    float v = (k < kmax) ? W[row*ldk + k] : 0.f;
    unsigned short hb = f2bf(v);
    f.hi[j] = (short)hb;
    f.lo[j] = (short)f2bf(v - bf2f(hb));
  }
  return f;
}

// ---- GRU: 2 layers, split-wave skewed pipeline + fused ac epilogue ----
// waves 0-3 (A): layer 0 at step t; waves 4-7 (B): layer 1 at step t-1.
// Epilogue: final h for the block's 16 nodes is on-chip -> compute the 8
// per-node scalars (a0,c0,a1,c1,a2,c2,g,p0) directly; hfin/ac_kernel deleted.
__global__ __launch_bounds__(512, 2)
void gru_kernel(const float* __restrict__ x,
                const float* __restrict__ Wih0, const float* __restrict__ Whh0,
                const float* __restrict__ bih0, const float* __restrict__ bhh0,
                const float* __restrict__ Wih1, const float* __restrict__ Whh1,
                const float* __restrict__ bih1, const float* __restrict__ bhh1,
                const float* __restrict__ W0h, const float* __restrict__ W1h,
                const float* __restrict__ W2h,
                const float* __restrict__ fcw, const float* __restrict__ fcb,
                float* __restrict__ ac){
  __shared__ unsigned short xp_hi[16][60][8];
  __shared__ unsigned short xp_lo[16][60][8];
  __shared__ unsigned short h0hi[2][16][72], h0lo[2][16][72];
  __shared__ unsigned short h1hi[2][16][72], h1lo[2][16][72];
  __shared__ float hsh[16][64];

  const int tid  = threadIdx.x;
  const int lane = tid & 63;
  const int wv   = tid >> 6;          // 0..7
  const bool isA = (wv < 4);          // wave-uniform
  const int w    = wv & 3;
  const int c    = lane & 15;
  const int q    = lane >> 4;
  const int d    = w*16 + c;
  const int nbase = blockIdx.x * 16;

  for (int v = tid; v < 16*360; v += 512){
    int n = v / 360, rem = v % 360;
    int dd = rem / 60, tt = rem % 60;
    float f = x[(size_t)(nbase + n)*360 + rem];
    unsigned short hb = f2bf(f);
    xp_hi[n][tt][dd] = hb;
    xp_lo[n][tt][dd] = f2bf(f - bf2f(hb));
  }
  for (int v = tid; v < 16*60*2; v += 512){
    int n = v / 120, rem = v % 120;
    int tt = rem >> 1, dd = 6 + (rem & 1);
    xp_hi[n][tt][dd] = 0; xp_lo[n][tt][dd] = 0;
  }
  for (int v = tid; v < 2*16*72; v += 512){
    ((unsigned short*)h0hi)[v] = 0; ((unsigned short*)h0lo)[v] = 0;
    ((unsigned short*)h1hi)[v] = 0; ((unsigned short*)h1lo)[v] = 0;
  }

  const float* bib = isA ? bih0 : bih1;
  const float* bhb = isA ? bhh0 : bhh1;
  const float bir = bib[d], biz = bib[64+d], bin = bib[128+d];
  const float bhr = bhb[d], bhz = bhb[64+d], bhn = bhb[128+d];

  WF Bu[3][2], Bv[3][2];
  #pragma unroll
  for (int g = 0; g < 3; g++){
    int row = g*64 + d;
    if (isA){
      Bu[g][0] = load_wf(Wih0, 6, row, q*8, 6);
      Bu[g][1] = Bu[g][0];
      #pragma unroll
      for (int kt = 0; kt < 2; kt++)
        Bv[g][kt] = load_wf(Whh0, 64, row, kt*32 + q*8, 64);
    } else {
      #pragma unroll
      for (int kt = 0; kt < 2; kt++){
        Bu[g][kt] = load_wf(Wih1, 64, row, kt*32 + q*8, 64);
        Bv[g][kt] = load_wf(Whh1, 64, row, kt*32 + q*8, 64);
      }
    }
  }

  float hold[4] = {0,0,0,0};

  auto stepB = [&](int s){
    const int rb = (s + 1) & 1;
    const int sb = s & 1;
    bf16x8 ayh[2], ayl[2], ahh[2], ahl[2];
    #pragma unroll
    for (int kt = 0; kt < 2; kt++){
      ayh[kt] = *(const bf16x8*)&h0hi[rb][c][kt*32 + q*8];
      ayl[kt] = *(const bf16x8*)&h0lo[rb][c][kt*32 + q*8];
      ahh[kt] = *(const bf16x8*)&h1hi[sb][c][kt*32 + q*8];
      ahl[kt] = *(const bf16x8*)&h1lo[sb][c][kt*32 + q*8];
    }
    f32x4 RH = {0,0,0,0}, RL = {0,0,0,0};
    f32x4 ZH = {0,0,0,0}, ZL = {0,0,0,0};
    f32x4 NIH = {0,0,0,0}, NIL = {0,0,0,0};
    f32x4 NHH = {0,0,0,0}, NHL = {0,0,0,0};
    #pragma unroll
    for (int kt = 0; kt < 2; kt++){
      mmsplit(ayh[kt], ayl[kt], Bu[0][kt], RH, RL);
      mmsplit(ayh[kt], ayl[kt], Bu[1][kt], ZH, ZL);
      mmsplit(ayh[kt], ayl[kt], Bu[2][kt], NIH, NIL);
      mmsplit(ahh[kt], ahl[kt], Bv[0][kt], RH, RL);
      mmsplit(ahh[kt], ahl[kt], Bv[1][kt], ZH, ZL);
      mmsplit(ahh[kt], ahl[kt], Bv[2][kt], NHH, NHL);
    }
    #pragma unroll
    for (int rI = 0; rI < 4; rI++){
      float rv = sigmoidf_(RH[rI] + RL[rI] + bir + bhr);
      float zv = sigmoidf_(ZH[rI] + ZL[rI] + biz + bhz);
      float nv = tanhf_(NIH[rI] + NIL[rI] + bin + rv*(NHH[rI] + NHL[rI] + bhn));
      float hnew = (1.f - zv)*nv + zv*hold[rI];
      hold[rI] = hnew;
      unsigned short hb = f2bf(hnew);
      int node = q*4 + rI;
      h1hi[rb][node][d] = hb;
      h1lo[rb][node][d] = f2bf(hnew - bf2f(hb));
    }
  };

  __syncthreads();

  #pragma unroll 1
  for (int t = 0; t < 60; t++){
    if (isA){
      const int p  = t & 1;
      const int nb = p ^ 1;
      bf16x8 ah[2], al[2];
      #pragma unroll
      for (int kt = 0; kt < 2; kt++){
        ah[kt] = *(const bf16x8*)&h0hi[p][c][kt*32 + q*8];
        al[kt] = *(const bf16x8*)&h0lo[p][c][kt*32 + q*8];
      }
      bf16x8 axh = {}, axl = {};
      if (q == 0){
        axh = *(const bf16x8*)&xp_hi[c][t][0];
        axl = *(const bf16x8*)&xp_lo[c][t][0];
      }
      f32x4 RH = {0,0,0,0}, RL = {0,0,0,0};
      f32x4 ZH = {0,0,0,0}, ZL = {0,0,0,0};
      f32x4 NIH = {0,0,0,0}, NIL = {0,0,0,0};
      f32x4 NHH = {0,0,0,0}, NHL = {0,0,0,0};
      mmsplit(axh, axl, Bu[0][0], RH, RL);
      mmsplit(axh, axl, Bu[1][0], ZH, ZL);
      mmsplit(axh, axl, Bu[2][0], NIH, NIL);
      #pragma unroll
      for (int kt = 0; kt < 2; kt++){
        mmsplit(ah[kt], al[kt], Bv[0][kt], RH, RL);
        mmsplit(ah[kt], al[kt], Bv[1][kt], ZH, ZL);
        mmsplit(ah[kt], al[kt], Bv[2][kt], NHH, NHL);
      }
      #pragma unroll
      for (int rI = 0; rI < 4; rI++){
        float rv = sigmoidf_(RH[rI] + RL[rI] + bir + bhr);
        float zv = sigmoidf_(ZH[rI] + ZL[rI] + biz + bhz);
        float nv = tanhf_(NIH[rI] + NIL[rI] + bin + rv*(NHH[rI] + NHL[rI] + bhn));
        float hnew = (1.f - zv)*nv + zv*hold[rI];
        hold[rI] = hnew;
        unsigned short hb = f2bf(hnew);
        int node = q*4 + rI;
        h0hi[nb][node][d] = hb;
        h0lo[nb][node][d] = f2bf(hnew - bf2f(hb));
      }
    } else if (t > 0){
      stepB(t - 1);
    }
    __syncthreads();
  }

  if (!isA){
    stepB(59);
    #pragma unroll
    for (int rI = 0; rI < 4; rI++)
      hsh[q*4 + rI][d] = hold[rI];
  }
  __syncthreads();

  // fused ac epilogue: all 8 waves, 2 nodes each; same shfl ladder as old
  // ac_kernel -> bit-identical results.
  {
    const float w0a = W0h[lane], w0c = W0h[64 + lane];
    const float w1a = W1h[lane], w1c = W1h[64 + lane];
    const float w2a = W2h[lane], w2c = W2h[64 + lane];
    const float gw  = fcw[64 + lane], pw = fcw[lane];
    #pragma unroll
    for (int nn = 0; nn < 2; nn++){
      int n = wv*2 + nn;
      float hv = hsh[n][lane];
      float pa0 = hv*w0a, pc0 = hv*w0c;
      float pa1 = hv*w1a, pc1 = hv*w1c;
      float pa2 = hv*w2a, pc2 = hv*w2c;
      float pg  = hv*gw,  pp  = hv*pw;
      #pragma unroll
      for (int m = 32; m >= 1; m >>= 1){
        pa0 += __shfl_xor(pa0, m, 64); pc0 += __shfl_xor(pc0, m, 64);
        pa1 += __shfl_xor(pa1, m, 64); pc1 += __shfl_xor(pc1, m, 64);
        pa2 += __shfl_xor(pa2, m, 64); pc2 += __shfl_xor(pc2, m, 64);
        pg  += __shfl_xor(pg,  m, 64); pp  += __shfl_xor(pp,  m, 64);
      }
      if (lane == 0){
        size_t node = (size_t)(nbase + n);
        ac[0*4000 + node] = pa0; ac[1*4000 + node] = pc0;
        ac[2*4000 + node] = pa1; ac[3*4000 + node] = pc1;
        ac[4*4000 + node] = pa2; ac[5*4000 + node] = pc2;
        ac[6*4000 + node] = pg;  ac[7*4000 + node] = pp + fcb[0];
      }
    }
  }
}

// -------- single-pass fused attention: z_h = Σ exp(v), y_h = Σ exp(v)·g[j] --------
// pred[i] = p0[i] + (1/3) Σ_h y_h/z_h.
__global__ __launch_bounds__(256, 4)
void attn2_kernel(const float* __restrict__ rel, const float* __restrict__ ac,
                  const float* __restrict__ b0p, const float* __restrict__ b1p,
                  const float* __restrict__ b2p, float* __restrict__ pred){
  __shared__ float red[4][12];

  const int tid  = threadIdx.x;
  const int lane = tid & 63;
  const int w    = tid >> 6;
  const int i0   = blockIdx.x * 2;
  const float bh[3] = {b0p[0], b1p[0], b2p[0]};

  const float* c0 = ac + (size_t)1*4000;
  const float* c1 = ac + (size_t)3*4000;
  const float* c2 = ac + (size_t)5*4000;
  const float* gv = ac + (size_t)6*4000;
  const float* p0 = ac + (size_t)7*4000;

  float ai[2][3];
  #pragma unroll
  for (int r = 0; r < 2; r++)
    #pragma unroll
    for (int h = 0; h < 3; h++)
      ai[r][h] = ac[(size_t)(2*h)*4000 + i0 + r];

  float z[2][3] = {{0.f,0.f,0.f},{0.f,0.f,0.f}};
  float y[2][3] = {{0.f,0.f,0.f},{0.f,0.f,0.f}};

  // single pass: stream rel once with depth-2 register prefetch
  {
    const size_t base0 = (size_t)i0*4000;
    const size_t base1 = (size_t)(i0+1)*4000;
    int j = tid;
    bool hv0 = (j < 4000);
    bool hv1 = (j + 256 < 4000);
    f4v a0, a1, a2, a3, b0, b1, b2, b3;
    if (hv0){
      const f4v* rp0 = (const f4v*)(rel + (base0 + j)*8);
      const f4v* rp1 = (const f4v*)(rel + (base1 + j)*8);
      a0 = __builtin_nontemporal_load(rp0);
      a1 = __builtin_nontemporal_load(rp0 + 1);
      a2 = __builtin_nontemporal_load(rp1);
      a3 = __builtin_nontemporal_load(rp1 + 1);
    }
    if (hv1){
      const f4v* rp0 = (const f4v*)(rel + (base0 + j + 256)*8);
      const f4v* rp1 = (const f4v*)(rel + (base1 + j + 256)*8);
      b0 = __builtin_nontemporal_load(rp0);
      b1 = __builtin_nontemporal_load(rp0 + 1);
      b2 = __builtin_nontemporal_load(rp1);
      b3 = __builtin_nontemporal_load(rp1 + 1);
    }
    while (hv0){
      int j2 = j + 512;
      bool hv2 = (j2 < 4000);
      f4v n0, n1, n2, n3;
      if (hv2){
        const f4v* rp0 = (const f4v*)(rel + (base0 + j2)*8);
        const f4v* rp1 = (const f4v*)(rel + (base1 + j2)*8);
        n0 = __builtin_nontemporal_load(rp0);
        n1 = __builtin_nontemporal_load(rp0 + 1);
        n2 = __builtin_nontemporal_load(rp1);
        n3 = __builtin_nontemporal_load(rp1 + 1);
      }
      float mk0 = a0[0]+a0[1]+a0[2]+a0[3] + a1[0]+a1[1]+a1[2]+a1[3];
      float mk1 = a2[0]+a2[1]+a2[2]+a2[3] + a3[0]+a3[1]+a3[2]+a3[3];
      float cv[3] = {c0[j], c1[j], c2[j]};
      float gj = gv[j];
      #pragma unroll
      for (int h = 0; h < 3; h++){
        float s0 = ai[0][h] + cv[h] + bh[h];
        float s1 = ai[1][h] + cv[h] + bh[h];
        float w0 = s0 > 0.f ? s0 : 0.01f*s0;
        float w1 = s1 > 0.f ? s1 : 0.01f*s1;
        float v0 = (mk0 == 0.f) ? -1e6f : mk0*w0;
        float v1 = (mk1 == 0.f) ? -1e6f : mk1*w1;
        float e0 = __expf(v0);
        float e1 = __expf(v1);
        z[0][h] += e0;  y[0][h] = fmaf(e0, gj, y[0][h]);
        z[1][h] += e1;  y[1][h] = fmaf(e1, gj, y[1][h]);
      }
      a0 = b0; a1 = b1; a2 = b2; a3 = b3;
      b0 = n0; b1 = n1; b2 = n2; b3 = n3;
      j += 256; hv0 = hv1; hv1 = hv2;
    }
  }

  // wave-reduce 12 (z,y) pairs, then cross-wave via tiny LDS
  #pragma unroll
  for (int r = 0; r < 2; r++)
    #pragma unroll
    for (int h = 0; h < 3; h++){
      float vz = z[r][h], vy = y[r][h];
      #pragma unroll
      for (int m = 32; m >= 1; m >>= 1){
        vz += __shfl_xor(vz, m, 64);
        vy += __shfl_xor(vy, m, 64);
      }
      if (lane == 0){
        red[w][(r*3 + h)*2 + 0] = vz;
        red[w][(r*3 + h)*2 + 1] = vy;
      }
    }
  __syncthreads();
  if (tid < 2){
    int r = tid;
    float acc = 0.f;
    #pragma unroll
    for (int h = 0; h < 3; h++){
      float zz = red[0][(r*3+h)*2] + red[1][(r*3+h)*2] + red[2][(r*3+h)*2] + red[3][(r*3+h)*2];
      float yy = red[0][(r*3+h)*2+1] + red[1][(r*3+h)*2+1] + red[2][(r*3+h)*2+1] + red[3][(r*3+h)*2+1];
      acc += yy / zz;
    }
    pred[i0 + r] = p0[i0 + r] + acc * (1.f/3.f);
  }
}

extern "C" void kernel_launch(void* const* d_in, const int* in_sizes, int n_in,
                              void* d_out, int out_size, void* d_ws, size_t ws_size,
                              hipStream_t stream) {
  const float* x    = (const float*)d_in[0];
  const float* rel  = (const float*)d_in[1];
  const float* Wih0 = (const float*)d_in[2];
  const float* Whh0 = (const float*)d_in[3];
  const float* bih0 = (const float*)d_in[4];
  const float* bhh0 = (const float*)d_in[5];
  const float* Wih1 = (const float*)d_in[6];
  const float* Whh1 = (const float*)d_in[7];
  const float* bih1 = (const float*)d_in[8];
  const float* bhh1 = (const float*)d_in[9];
  const float* W0   = (const float*)d_in[10];
  const float* b0   = (const float*)d_in[11];
  const float* W1   = (const float*)d_in[12];
  const float* b1   = (const float*)d_in[13];
  const float* W2   = (const float*)d_in[14];
  const float* b2   = (const float*)d_in[15];
  const float* fcw  = (const float*)d_in[16];
  const float* fcb  = (const float*)d_in[17];
  float* pred = (float*)d_out;
  float* ac   = (float*)d_ws;          // 8*4000 f32: a0,c0,a1,c1,a2,c2,g,p0

  gru_kernel<<<dim3(250), dim3(512), 0, stream>>>(x, Wih0, Whh0, bih0, bhh0,
                                                  Wih1, Whh1, bih1, bhh1,
                                                  W0, W1, W2, fcw, fcb, ac);
  attn2_kernel<<<dim3(2000), dim3(256), 0, stream>>>(rel, ac, b0, b1, b2, pred);
}